// Round 16
// baseline (368.393 us; speedup 1.0000x reference)
//
#include <hip/hip_runtime.h>
#include <hip/hip_bf16.h>
#include <math.h>

// Problem: S=128, B=16, D=H=512, O=256.
// Collapse 1: watch/sus are exactly s-independent -> [16,512] recurrence;
//             outs broadcasts [128,16,256].
// Collapse 2: recurrence is row-independent -> 16 independent b-recurrences.
// Pipeline = R15 (MFMA prologue -> recurrence -> dual GEMM -> fused epilogue).
// R16 changes: (1) sus_scan fused into finalize (scan 4-wide ILP, hidden
// under the 268 MB outs stream; one launch fewer); (2) recurrence issues the
// per-step weight loads BEFORE the poll loop (sched_barrier pin) so their
// L2 round trip overlaps the poll's first LLC round trip (vmcnt(0) drains
// both concurrently) instead of serializing after detect.
// Recurrence sync: wave-local poll (wave kq's 64 lanes poll exactly its FMA
// input range), wave-private wsm + lgkmcnt(0)+sched_barrier (rule #18), ONE
// syncthreads/step for the parity-dbuf red reduce.
// Epoch-in-data u64 (epoch<<32|f32 bits): 0xAA poison never matches epoch t;
// values deterministic -> stale/cross-replay matches are bit-identical/safe.
// GEMMs: MFMA split-bf16 (hi/lo, 3 mfma_16x16x32 per pair, ~2^-16 rel err).

#define S_LEN 128
#define B_SZ  16
#define H_SZ  512
#define O_SZ  256
#define ROWS  (S_LEN * B_SZ)   // 2048

#define OUTS_ELEMS  (S_LEN * S_LEN * B_SZ * O_SZ)   // 67,108,864
#define WATCH_ELEMS (S_LEN * B_SZ * H_SZ)           // 1,048,576

typedef float  f32x4  __attribute__((ext_vector_type(4)));
typedef __bf16 bf16x8 __attribute__((ext_vector_type(8)));

// ================= MFMA split-bf16 GEMM =====================================
struct alignas(16) GemmLds {
  __bf16 Ah[64][40]; __bf16 Al[64][40];
  __bf16 Bh[64][40]; __bf16 Bl[64][40];
};

__device__ __forceinline__ void gemm_body(
    const float* __restrict__ A, const float* __restrict__ B,
    const float* __restrict__ bias0, const float* __restrict__ bias1,
    float* __restrict__ C, int N, int K, int bm, int bn, GemmLds& T)
{
  const int tid = threadIdx.x;
  const int w = tid >> 6, l = tid & 63;
  const int fr = l & 15, fg = l >> 4;
  f32x4 acc[4] = {{0,0,0,0},{0,0,0,0},{0,0,0,0},{0,0,0,0}};
  const int ar = tid >> 2, ak = (tid & 3) << 3;   // A staging: row, k8
  const int bk = tid >> 3, bc = (tid & 7) << 3;   // B staging: k, col8

  for (int k0 = 0; k0 < K; k0 += 32) {
    {
      const float* s = &A[(size_t)(bm + ar) * K + k0 + ak];
      const f32x4 v0 = *(const f32x4*)s, v1 = *(const f32x4*)(s + 4);
      const float vv[8] = {v0.x, v0.y, v0.z, v0.w, v1.x, v1.y, v1.z, v1.w};
      bf16x8 h, lo;
#pragma unroll
      for (int j = 0; j < 8; ++j) {
        const __bf16 hh = (__bf16)vv[j];
        h[j] = hh; lo[j] = (__bf16)(vv[j] - (float)hh);
      }
      *(bf16x8*)&T.Ah[ar][ak] = h;
      *(bf16x8*)&T.Al[ar][ak] = lo;
    }
    {
      const float* s = &B[(size_t)(k0 + bk) * N + bn + bc];
      const f32x4 v0 = *(const f32x4*)s, v1 = *(const f32x4*)(s + 4);
      const float vv[8] = {v0.x, v0.y, v0.z, v0.w, v1.x, v1.y, v1.z, v1.w};
#pragma unroll
      for (int j = 0; j < 8; ++j) {
        const __bf16 hh = (__bf16)vv[j];
        T.Bh[bc + j][bk] = hh;
        T.Bl[bc + j][bk] = (__bf16)(vv[j] - (float)hh);
      }
    }
    __syncthreads();
    const bf16x8 ah = *(const bf16x8*)&T.Ah[(w << 4) + fr][fg << 3];
    const bf16x8 al = *(const bf16x8*)&T.Al[(w << 4) + fr][fg << 3];
#pragma unroll
    for (int nr = 0; nr < 4; ++nr) {
      const bf16x8 bh = *(const bf16x8*)&T.Bh[(nr << 4) + fr][fg << 3];
      const bf16x8 bl = *(const bf16x8*)&T.Bl[(nr << 4) + fr][fg << 3];
      acc[nr] = __builtin_amdgcn_mfma_f32_16x16x32_bf16(ah, bh, acc[nr], 0, 0, 0);
      acc[nr] = __builtin_amdgcn_mfma_f32_16x16x32_bf16(al, bh, acc[nr], 0, 0, 0);
      acc[nr] = __builtin_amdgcn_mfma_f32_16x16x32_bf16(ah, bl, acc[nr], 0, 0, 0);
    }
    __syncthreads();
  }
#pragma unroll
  for (int nr = 0; nr < 4; ++nr) {
    const int gcol = bn + (nr << 4) + fr;
    float bb = bias0 ? bias0[gcol] : 0.f;
    if (bias1) bb += bias1[gcol];
#pragma unroll
    for (int r = 0; r < 4; ++r) {
      const int grow = bm + (w << 4) + (fg << 2) + r;
      C[(size_t)grow * N + gcol] = acc[nr][r] + bb;
    }
  }
}

__global__ __launch_bounds__(256) void gemm_mfma(
    const float* __restrict__ A, const float* __restrict__ B,
    const float* __restrict__ bias0, const float* __restrict__ bias1,
    float* __restrict__ C, int N, int K)
{
  __shared__ GemmLds T;
  gemm_body(A, B, bias0, bias1, C, N, K, blockIdx.y << 6, blockIdx.x << 6, T);
}

__global__ __launch_bounds__(256) void gemm_dual_mfma(
    const float* __restrict__ A,
    const float* __restrict__ B1, const float* __restrict__ b1, float* __restrict__ C1,
    const float* __restrict__ B2, const float* __restrict__ b2, float* __restrict__ C2)
{
  __shared__ GemmLds T;
  if (blockIdx.x < 8)
    gemm_body(A, B1, b1, nullptr, C1, 512, 512, blockIdx.y << 6, blockIdx.x << 6, T);
  else
    gemm_body(A, B2, b2, nullptr, C2, 256, 512, blockIdx.y << 6, (blockIdx.x - 8) << 6, T);
}

// ---------------- softmax over H then gate by x (in-place on logits) --------
__global__ __launch_bounds__(64) void softmax_gate(float* __restrict__ lg,
                                                   const float* __restrict__ x)
{
  const int r = blockIdx.x;      // 0..2047
  const int lane = threadIdx.x;  // 0..63
  float v[8];
  float m = -1e30f;
#pragma unroll
  for (int i = 0; i < 8; ++i) {
    v[i] = lg[(r << 9) + (i << 6) + lane];
    m = fmaxf(m, v[i]);
  }
#pragma unroll
  for (int off = 32; off > 0; off >>= 1) m = fmaxf(m, __shfl_xor(m, off, 64));
  float s = 0.f;
#pragma unroll
  for (int i = 0; i < 8; ++i) { v[i] = expf(v[i] - m); s += v[i]; }
#pragma unroll
  for (int off = 32; off > 0; off >>= 1) s += __shfl_xor(s, off, 64);
  const float inv = 1.0f / s;
#pragma unroll
  for (int i = 0; i < 8; ++i) {
    const int idx = (r << 9) + (i << 6) + lane;
    lg[idx] = v[i] * inv * x[idx];
  }
}

// ---------------- recurrence (wave-local poll + weight-load hoist) ----------
// 128 WGs = 16 b x 8 parts; part owns cols [64p,64p+64); wave kq owns K-range
// [128kq,128kq+128). Thread tid polls pz[2tid,2tid+1] (exactly its wave's FMA
// input range). Weight loads issued BEFORE the poll (sched_barrier pin) so
// their L2 RT overlaps the poll's LLC RT (vmcnt(0) drains both concurrently).
__global__ __launch_bounds__(256, 1) void recurrence(
    const float* __restrict__ cbuf,          // [128][16][512]
    const float* __restrict__ insw,          // [512][512]
    float* __restrict__ wall,                // [128][16][512]
    unsigned long long* __restrict__ pz)     // [16][16][512] u64 ring
{
  __shared__ float wsm[H_SZ];        // wave-private slices (wave kq: [128kq,+128))
  __shared__ float red[2][4][64];    // parity-dbuf cross-wave reduce

  const int wg  = blockIdx.x;
  const int b   = wg & 15;
  const int p   = wg >> 4;           // 0..7
  const int tid = threadIdx.x;
  const int cl  = tid & 63;
  const int kq  = tid >> 6;          // wave 0..3
  const int c   = (p << 6) + cl;     // owned col
  const int kbase = kq << 7;

  // t = 0: publish w0 = tanh(c0) with epoch 1 in slot 0
  if (tid < 64) {
    const float v = tanhf(cbuf[(b << 9) + c]);
    wall[(b << 9) + c] = v;
    const unsigned long long pk =
        (1ULL << 32) | (unsigned long long)__float_as_uint(v);
    __hip_atomic_store(&pz[(b << 9) + c], pk, __ATOMIC_RELAXED,
                       __HIP_MEMORY_SCOPE_AGENT);
  }

  for (int t = 1; t < S_LEN; ++t) {
    // independent loads issued before the poll: c_t and this step's weights
    const float cv = cbuf[(t << 13) + (b << 9) + c];
    float wrf[128];
#pragma unroll
    for (int j = 0; j < 128; ++j)
      wrf[j] = insw[((kbase + j) << 9) + c];
    __builtin_amdgcn_sched_barrier(0);           // pin issue before the poll

    // wave-local poll: this wave's 64 lanes cover exactly [128kq,128kq+128)
    const unsigned long long* src =
        pz + (((t - 1) & 15) << 13) + (b << 9);
    unsigned long long v0, v1;
    for (;;) {
      v0 = __hip_atomic_load(&src[2 * tid], __ATOMIC_RELAXED,
                             __HIP_MEMORY_SCOPE_AGENT);
      v1 = __hip_atomic_load(&src[2 * tid + 1], __ATOMIC_RELAXED,
                             __HIP_MEMORY_SCOPE_AGENT);
      const bool ok = ((unsigned)(v0 >> 32) == (unsigned)t) &
                      ((unsigned)(v1 >> 32) == (unsigned)t);
      if (__ballot(ok) == ~0ULL) break;          // wave-local exit
    }
    // wave-private forwarding (only this wave reads this wsm range)
    wsm[2 * tid]     = __uint_as_float((unsigned)v0);
    wsm[2 * tid + 1] = __uint_as_float((unsigned)v1);
    asm volatile("s_waitcnt lgkmcnt(0)" ::: "memory");
    __builtin_amdgcn_sched_barrier(0);           // rule #18

    // partial dot over this wave's K range: 128 exact f32 FMAs
    float a0 = 0.f, a1 = 0.f, a2 = 0.f, a3 = 0.f;
#pragma unroll
    for (int j = 0; j < 32; ++j) {
      const f32x4 wv = *(const f32x4*)&wsm[kbase + (j << 2)];
      a0 = fmaf(wrf[4 * j + 0], wv.x, a0);
      a1 = fmaf(wrf[4 * j + 1], wv.y, a1);
      a2 = fmaf(wrf[4 * j + 2], wv.z, a2);
      a3 = fmaf(wrf[4 * j + 3], wv.w, a3);
    }
    red[t & 1][kq][cl] = (a0 + a1) + (a2 + a3);
    __syncthreads();                             // the ONE barrier per step
    if (tid < 64) {
      const float y = red[t & 1][0][cl] + red[t & 1][1][cl] +
                      red[t & 1][2][cl] + red[t & 1][3][cl];
      const float v = tanhf(cv + y);
      wall[(t << 13) + (b << 9) + c] = v;
      const unsigned long long pk =
          ((unsigned long long)(unsigned)(t + 1) << 32) |
          (unsigned long long)__float_as_uint(v);
      __hip_atomic_store(&pz[((t & 15) << 13) + (b << 9) + c], pk,
                         __ATOMIC_RELAXED, __HIP_MEMORY_SCOPE_AGENT);
    }
  }
}

// ---------------- finalize: outs + watch bc + fused sus scan+bc -------------
// blocks 0..4095: outs broadcast (268 MB nontemporal) + watch bc (4 MB).
// blocks 4096..4103: 2048 threads, 4-wide-ILP sus scan from mbuf -> sus bc.
__global__ __launch_bounds__(256) void finalize(
    const f32x4* __restrict__ os4, f32x4* __restrict__ outs4,
    const f32x4* __restrict__ w127, const f32x4* __restrict__ M4,
    f32x4* __restrict__ watch_out, f32x4* __restrict__ sus_out)
{
  const int bid = blockIdx.x;
  if (bid < 4096) {
    const int gid = bid * 256 + threadIdx.x;
    for (int i = gid; i < (1 << 24); i += 4096 * 256) {
      const int o4 = i & 63;
      const int b  = (i >> 6) & 15;
      const int t  = i >> 17;
      __builtin_nontemporal_store(os4[(((t << 4) + b) << 6) + o4], &outs4[i]);
    }
    if (gid < (1 << 18))
      __builtin_nontemporal_store(w127[gid & 2047], &watch_out[gid]);
  } else {
    const int gid = (bid - 4096) * 256 + threadIdx.x;  // 0..2047 (f32x4 lanes)
    f32x4 n0 = M4[gid];
    f32x4 n1 = M4[(1 << 11) + gid];
    f32x4 n2 = M4[(2 << 11) + gid];
    f32x4 n3 = M4[(3 << 11) + gid];
    float sx = 0.f, sy = 0.f, sz = 0.f, sw = 0.f;
    for (int t = 0; t < S_LEN - 4; ++t) {
      const f32x4 cur = n0;
      n0 = n1; n1 = n2; n2 = n3;
      n3 = M4[((t + 4) << 11) + gid];
      sx = tanhf(cur.x + sx); sy = tanhf(cur.y + sy);
      sz = tanhf(cur.z + sz); sw = tanhf(cur.w + sw);
    }
    sx = tanhf(n0.x + sx); sy = tanhf(n0.y + sy);
    sz = tanhf(n0.z + sz); sw = tanhf(n0.w + sw);
    sx = tanhf(n1.x + sx); sy = tanhf(n1.y + sy);
    sz = tanhf(n1.z + sz); sw = tanhf(n1.w + sw);
    sx = tanhf(n2.x + sx); sy = tanhf(n2.y + sy);
    sz = tanhf(n2.z + sz); sw = tanhf(n2.w + sw);
    sx = tanhf(n3.x + sx); sy = tanhf(n3.y + sy);
    sz = tanhf(n3.z + sz); sw = tanhf(n3.w + sw);
    const f32x4 s = {sx, sy, sz, sw};
#pragma unroll 4
    for (int si = 0; si < S_LEN; ++si)
      __builtin_nontemporal_store(s, &sus_out[(si << 11) + gid]);
  }
}

extern "C" void kernel_launch(void* const* d_in, const int* in_sizes, int n_in,
                              void* d_out, int out_size, void* d_ws, size_t ws_size,
                              hipStream_t stream)
{
  const float* x      = (const float*)d_in[0];
  const float* attn_w = (const float*)d_in[1];
  const float* attn_b = (const float*)d_in[2];
  const float* in_w   = (const float*)d_in[3];
  const float* in_b   = (const float*)d_in[4];
  const float* ins_w  = (const float*)d_in[5];
  const float* ins_b  = (const float*)d_in[6];
  const float* sus_w  = (const float*)d_in[7];
  const float* sus_b  = (const float*)d_in[8];
  const float* out_w  = (const float*)d_in[9];
  const float* out_b  = (const float*)d_in[10];

  // ws (bytes): cbuf [0,4M) | wall [4M,8M) | tmp->mbuf [8M,12M) | pz [12M,13M)
  // after recurrence, cbuf region reused: obuf [0,2M)
  float* ws    = (float*)d_ws;
  float* cbuf  = ws;
  float* wallb = ws + (1 << 20);
  float* tmp   = ws + (2 << 20);
  float* mbuf  = tmp;
  unsigned long long* pz = (unsigned long long*)(ws + (3 << 20));
  float* obuf  = ws;

  float* outp   = (float*)d_out;
  float* watchp = outp + OUTS_ELEMS;
  float* susp   = watchp + WATCH_ELEMS;

  const dim3 blk(256);
  // logits = X @ attn_w + attn_b -> tmp   (MFMA split-bf16)
  gemm_mfma<<<dim3(8, 32), blk, 0, stream>>>(x, attn_w, attn_b, nullptr, tmp, 512, 512);
  // R = softmax(logits) * X   (in place on tmp)
  softmax_gate<<<dim3(2048), dim3(64), 0, stream>>>(tmp, x);
  // c = R @ in_w + in_b + ins_b -> cbuf
  gemm_mfma<<<dim3(8, 32), blk, 0, stream>>>(tmp, in_w, in_b, ins_b, cbuf, 512, 512);
  // sequential recurrence (no memset — epoch scheme replay-safe)
  recurrence<<<dim3(128), blk, 0, stream>>>(cbuf, ins_w, wallb, pz);
  // M = wall @ sus_w + sus_b -> mbuf ; out_small = wall @ out_w + out_b -> obuf
  gemm_dual_mfma<<<dim3(12, 32), blk, 0, stream>>>(wallb, sus_w, sus_b, mbuf,
                                                   out_w, out_b, obuf);
  // outs broadcast (268 MB) + watch bc + fused sus scan+bc
  finalize<<<dim3(4104), blk, 0, stream>>>(
      (const f32x4*)obuf, (f32x4*)d_out,
      (const f32x4*)(wallb + (127 << 13)), (const f32x4*)mbuf,
      (f32x4*)watchp, (f32x4*)susp);
}

// Round 17
// 346.819 us; speedup vs baseline: 1.0622x; 1.0622x over previous
//
#include <hip/hip_runtime.h>
#include <hip/hip_bf16.h>
#include <math.h>

// Problem: S=128, B=16, D=H=512, O=256.
// Collapse 1: watch/sus are exactly s-independent -> [16,512] recurrence;
//             outs broadcasts [128,16,256].
// Collapse 2: recurrence is row-independent -> 16 independent b-recurrences.
// Pipeline: MFMA prologue -> recurrence (R15, proven 186 us) -> dual GEMM ->
// fused finalize. R17 fix vs R16: scan blocks FIRST (bid 0-7) so the serial
// sus scan runs UNDER the 268 MB outs broadcast instead of as a tail
// (R16's regression was scan blocks at bid 4096+ starting mid-broadcast).
// Recurrence sync: wave-local poll (wave kq's 64 lanes poll exactly its FMA
// input range), wave-private wsm + lgkmcnt(0)+sched_barrier (rule #18), ONE
// syncthreads/step for the parity-dbuf red reduce.
// Epoch-in-data u64 (epoch<<32|f32 bits): 0xAA poison never matches epoch t;
// values deterministic -> stale/cross-replay matches are bit-identical/safe.
// GEMMs: MFMA split-bf16 (hi/lo, 3 mfma_16x16x32 per pair, ~2^-16 rel err).

#define S_LEN 128
#define B_SZ  16
#define H_SZ  512
#define O_SZ  256
#define ROWS  (S_LEN * B_SZ)   // 2048

#define OUTS_ELEMS  (S_LEN * S_LEN * B_SZ * O_SZ)   // 67,108,864
#define WATCH_ELEMS (S_LEN * B_SZ * H_SZ)           // 1,048,576

typedef float  f32x4  __attribute__((ext_vector_type(4)));
typedef __bf16 bf16x8 __attribute__((ext_vector_type(8)));

// ================= MFMA split-bf16 GEMM =====================================
struct alignas(16) GemmLds {
  __bf16 Ah[64][40]; __bf16 Al[64][40];
  __bf16 Bh[64][40]; __bf16 Bl[64][40];
};

__device__ __forceinline__ void gemm_body(
    const float* __restrict__ A, const float* __restrict__ B,
    const float* __restrict__ bias0, const float* __restrict__ bias1,
    float* __restrict__ C, int N, int K, int bm, int bn, GemmLds& T)
{
  const int tid = threadIdx.x;
  const int w = tid >> 6, l = tid & 63;
  const int fr = l & 15, fg = l >> 4;
  f32x4 acc[4] = {{0,0,0,0},{0,0,0,0},{0,0,0,0},{0,0,0,0}};
  const int ar = tid >> 2, ak = (tid & 3) << 3;   // A staging: row, k8
  const int bk = tid >> 3, bc = (tid & 7) << 3;   // B staging: k, col8

  for (int k0 = 0; k0 < K; k0 += 32) {
    {
      const float* s = &A[(size_t)(bm + ar) * K + k0 + ak];
      const f32x4 v0 = *(const f32x4*)s, v1 = *(const f32x4*)(s + 4);
      const float vv[8] = {v0.x, v0.y, v0.z, v0.w, v1.x, v1.y, v1.z, v1.w};
      bf16x8 h, lo;
#pragma unroll
      for (int j = 0; j < 8; ++j) {
        const __bf16 hh = (__bf16)vv[j];
        h[j] = hh; lo[j] = (__bf16)(vv[j] - (float)hh);
      }
      *(bf16x8*)&T.Ah[ar][ak] = h;
      *(bf16x8*)&T.Al[ar][ak] = lo;
    }
    {
      const float* s = &B[(size_t)(k0 + bk) * N + bn + bc];
      const f32x4 v0 = *(const f32x4*)s, v1 = *(const f32x4*)(s + 4);
      const float vv[8] = {v0.x, v0.y, v0.z, v0.w, v1.x, v1.y, v1.z, v1.w};
#pragma unroll
      for (int j = 0; j < 8; ++j) {
        const __bf16 hh = (__bf16)vv[j];
        T.Bh[bc + j][bk] = hh;
        T.Bl[bc + j][bk] = (__bf16)(vv[j] - (float)hh);
      }
    }
    __syncthreads();
    const bf16x8 ah = *(const bf16x8*)&T.Ah[(w << 4) + fr][fg << 3];
    const bf16x8 al = *(const bf16x8*)&T.Al[(w << 4) + fr][fg << 3];
#pragma unroll
    for (int nr = 0; nr < 4; ++nr) {
      const bf16x8 bh = *(const bf16x8*)&T.Bh[(nr << 4) + fr][fg << 3];
      const bf16x8 bl = *(const bf16x8*)&T.Bl[(nr << 4) + fr][fg << 3];
      acc[nr] = __builtin_amdgcn_mfma_f32_16x16x32_bf16(ah, bh, acc[nr], 0, 0, 0);
      acc[nr] = __builtin_amdgcn_mfma_f32_16x16x32_bf16(al, bh, acc[nr], 0, 0, 0);
      acc[nr] = __builtin_amdgcn_mfma_f32_16x16x32_bf16(ah, bl, acc[nr], 0, 0, 0);
    }
    __syncthreads();
  }
#pragma unroll
  for (int nr = 0; nr < 4; ++nr) {
    const int gcol = bn + (nr << 4) + fr;
    float bb = bias0 ? bias0[gcol] : 0.f;
    if (bias1) bb += bias1[gcol];
#pragma unroll
    for (int r = 0; r < 4; ++r) {
      const int grow = bm + (w << 4) + (fg << 2) + r;
      C[(size_t)grow * N + gcol] = acc[nr][r] + bb;
    }
  }
}

__global__ __launch_bounds__(256) void gemm_mfma(
    const float* __restrict__ A, const float* __restrict__ B,
    const float* __restrict__ bias0, const float* __restrict__ bias1,
    float* __restrict__ C, int N, int K)
{
  __shared__ GemmLds T;
  gemm_body(A, B, bias0, bias1, C, N, K, blockIdx.y << 6, blockIdx.x << 6, T);
}

__global__ __launch_bounds__(256) void gemm_dual_mfma(
    const float* __restrict__ A,
    const float* __restrict__ B1, const float* __restrict__ b1, float* __restrict__ C1,
    const float* __restrict__ B2, const float* __restrict__ b2, float* __restrict__ C2)
{
  __shared__ GemmLds T;
  if (blockIdx.x < 8)
    gemm_body(A, B1, b1, nullptr, C1, 512, 512, blockIdx.y << 6, blockIdx.x << 6, T);
  else
    gemm_body(A, B2, b2, nullptr, C2, 256, 512, blockIdx.y << 6, (blockIdx.x - 8) << 6, T);
}

// ---------------- softmax over H then gate by x (in-place on logits) --------
__global__ __launch_bounds__(64) void softmax_gate(float* __restrict__ lg,
                                                   const float* __restrict__ x)
{
  const int r = blockIdx.x;      // 0..2047
  const int lane = threadIdx.x;  // 0..63
  float v[8];
  float m = -1e30f;
#pragma unroll
  for (int i = 0; i < 8; ++i) {
    v[i] = lg[(r << 9) + (i << 6) + lane];
    m = fmaxf(m, v[i]);
  }
#pragma unroll
  for (int off = 32; off > 0; off >>= 1) m = fmaxf(m, __shfl_xor(m, off, 64));
  float s = 0.f;
#pragma unroll
  for (int i = 0; i < 8; ++i) { v[i] = expf(v[i] - m); s += v[i]; }
#pragma unroll
  for (int off = 32; off > 0; off >>= 1) s += __shfl_xor(s, off, 64);
  const float inv = 1.0f / s;
#pragma unroll
  for (int i = 0; i < 8; ++i) {
    const int idx = (r << 9) + (i << 6) + lane;
    lg[idx] = v[i] * inv * x[idx];
  }
}

// ---------------- recurrence (R15: wave-local poll) -------------------------
// 128 WGs = 16 b x 8 parts; part owns cols [64p,64p+64); wave kq owns K-range
// [128kq,128kq+128). Thread tid polls pz[2tid,2tid+1] -> wave kq's 64 lanes
// poll exactly its FMA input range -> wave-local ballot exit, wave-private
// wsm (no barrier), ONE syncthreads/step for parity-dbuf red reduce.
__global__ __launch_bounds__(256, 1) void recurrence(
    const float* __restrict__ cbuf,          // [128][16][512]
    const float* __restrict__ insw,          // [512][512]
    float* __restrict__ wall,                // [128][16][512]
    unsigned long long* __restrict__ pz)     // [16][16][512] u64 ring
{
  __shared__ float wsm[H_SZ];        // wave-private slices (wave kq: [128kq,+128))
  __shared__ float red[2][4][64];    // parity-dbuf cross-wave reduce

  const int wg  = blockIdx.x;
  const int b   = wg & 15;
  const int p   = wg >> 4;           // 0..7
  const int tid = threadIdx.x;
  const int cl  = tid & 63;
  const int kq  = tid >> 6;          // wave 0..3
  const int c   = (p << 6) + cl;     // owned col
  const int kbase = kq << 7;

  // weights: wr[j][e] = ins_w[kbase+4j+e][c] (L2-restreamed; R4/R10-measured OK)
  f32x4 wr[32];
#pragma unroll
  for (int j = 0; j < 32; ++j) {
    wr[j].x = insw[((kbase + 4 * j + 0) << 9) + c];
    wr[j].y = insw[((kbase + 4 * j + 1) << 9) + c];
    wr[j].z = insw[((kbase + 4 * j + 2) << 9) + c];
    wr[j].w = insw[((kbase + 4 * j + 3) << 9) + c];
  }

  // t = 0: publish w0 = tanh(c0) with epoch 1 in slot 0
  if (tid < 64) {
    const float v = tanhf(cbuf[(b << 9) + c]);
    wall[(b << 9) + c] = v;
    const unsigned long long pk =
        (1ULL << 32) | (unsigned long long)__float_as_uint(v);
    __hip_atomic_store(&pz[(b << 9) + c], pk, __ATOMIC_RELAXED,
                       __HIP_MEMORY_SCOPE_AGENT);
  }

  for (int t = 1; t < S_LEN; ++t) {
    // prefetch c_t (independent of the chain)
    const float cv = cbuf[(t << 13) + (b << 9) + c];

    // wave-local poll: this wave's 64 lanes cover exactly [128kq,128kq+128)
    const unsigned long long* src =
        pz + (((t - 1) & 15) << 13) + (b << 9);
    unsigned long long v0, v1;
    for (;;) {
      v0 = __hip_atomic_load(&src[2 * tid], __ATOMIC_RELAXED,
                             __HIP_MEMORY_SCOPE_AGENT);
      v1 = __hip_atomic_load(&src[2 * tid + 1], __ATOMIC_RELAXED,
                             __HIP_MEMORY_SCOPE_AGENT);
      const bool ok = ((unsigned)(v0 >> 32) == (unsigned)t) &
                      ((unsigned)(v1 >> 32) == (unsigned)t);
      if (__ballot(ok) == ~0ULL) break;          // wave-local exit
    }
    // wave-private forwarding (only this wave reads this wsm range)
    wsm[2 * tid]     = __uint_as_float((unsigned)v0);
    wsm[2 * tid + 1] = __uint_as_float((unsigned)v1);
    asm volatile("s_waitcnt lgkmcnt(0)" ::: "memory");
    __builtin_amdgcn_sched_barrier(0);           // rule #18

    // partial dot over this wave's K range: 128 exact f32 FMAs
    float a0 = 0.f, a1 = 0.f, a2 = 0.f, a3 = 0.f;
#pragma unroll
    for (int j = 0; j < 32; ++j) {
      const f32x4 wv = *(const f32x4*)&wsm[kbase + (j << 2)];
      a0 = fmaf(wr[j].x, wv.x, a0);
      a1 = fmaf(wr[j].y, wv.y, a1);
      a2 = fmaf(wr[j].z, wv.z, a2);
      a3 = fmaf(wr[j].w, wv.w, a3);
    }
    red[t & 1][kq][cl] = (a0 + a1) + (a2 + a3);
    __syncthreads();                             // the ONE barrier per step
    if (tid < 64) {
      const float y = red[t & 1][0][cl] + red[t & 1][1][cl] +
                      red[t & 1][2][cl] + red[t & 1][3][cl];
      const float v = tanhf(cv + y);
      wall[(t << 13) + (b << 9) + c] = v;
      const unsigned long long pk =
          ((unsigned long long)(unsigned)(t + 1) << 32) |
          (unsigned long long)__float_as_uint(v);
      __hip_atomic_store(&pz[((t & 15) << 13) + (b << 9) + c], pk,
                         __ATOMIC_RELAXED, __HIP_MEMORY_SCOPE_AGENT);
    }
  }
}

// ---------------- finalize: fused sus scan FIRST + outs + watch bc ----------
// blocks 0..7 (dispatched first -> run under the broadcast): 4-wide-ILP sus
// scan from mbuf -> sus bc. blocks 8..4103: outs broadcast (268 MB) + watch.
__global__ __launch_bounds__(256) void finalize(
    const f32x4* __restrict__ os4, f32x4* __restrict__ outs4,
    const f32x4* __restrict__ w127, const f32x4* __restrict__ M4,
    f32x4* __restrict__ watch_out, f32x4* __restrict__ sus_out)
{
  const int bid = blockIdx.x;
  if (bid >= 8) {
    const int gid = (bid - 8) * 256 + threadIdx.x;
    for (int i = gid; i < (1 << 24); i += 4096 * 256) {
      const int o4 = i & 63;
      const int b  = (i >> 6) & 15;
      const int t  = i >> 17;
      __builtin_nontemporal_store(os4[(((t << 4) + b) << 6) + o4], &outs4[i]);
    }
    if (gid < (1 << 18))
      __builtin_nontemporal_store(w127[gid & 2047], &watch_out[gid]);
  } else {
    const int gid = bid * 256 + threadIdx.x;  // 0..2047 (f32x4 lanes)
    f32x4 n0 = M4[gid];
    f32x4 n1 = M4[(1 << 11) + gid];
    f32x4 n2 = M4[(2 << 11) + gid];
    f32x4 n3 = M4[(3 << 11) + gid];
    float sx = 0.f, sy = 0.f, sz = 0.f, sw = 0.f;
    for (int t = 0; t < S_LEN - 4; ++t) {
      const f32x4 cur = n0;
      n0 = n1; n1 = n2; n2 = n3;
      n3 = M4[((t + 4) << 11) + gid];
      sx = tanhf(cur.x + sx); sy = tanhf(cur.y + sy);
      sz = tanhf(cur.z + sz); sw = tanhf(cur.w + sw);
    }
    sx = tanhf(n0.x + sx); sy = tanhf(n0.y + sy);
    sz = tanhf(n0.z + sz); sw = tanhf(n0.w + sw);
    sx = tanhf(n1.x + sx); sy = tanhf(n1.y + sy);
    sz = tanhf(n1.z + sz); sw = tanhf(n1.w + sw);
    sx = tanhf(n2.x + sx); sy = tanhf(n2.y + sy);
    sz = tanhf(n2.z + sz); sw = tanhf(n2.w + sw);
    sx = tanhf(n3.x + sx); sy = tanhf(n3.y + sy);
    sz = tanhf(n3.z + sz); sw = tanhf(n3.w + sw);
    const f32x4 s = {sx, sy, sz, sw};
#pragma unroll 4
    for (int si = 0; si < S_LEN; ++si)
      __builtin_nontemporal_store(s, &sus_out[(si << 11) + gid]);
  }
}

extern "C" void kernel_launch(void* const* d_in, const int* in_sizes, int n_in,
                              void* d_out, int out_size, void* d_ws, size_t ws_size,
                              hipStream_t stream)
{
  const float* x      = (const float*)d_in[0];
  const float* attn_w = (const float*)d_in[1];
  const float* attn_b = (const float*)d_in[2];
  const float* in_w   = (const float*)d_in[3];
  const float* in_b   = (const float*)d_in[4];
  const float* ins_w  = (const float*)d_in[5];
  const float* ins_b  = (const float*)d_in[6];
  const float* sus_w  = (const float*)d_in[7];
  const float* sus_b  = (const float*)d_in[8];
  const float* out_w  = (const float*)d_in[9];
  const float* out_b  = (const float*)d_in[10];

  // ws (bytes): cbuf [0,4M) | wall [4M,8M) | tmp->mbuf [8M,12M) | pz [12M,13M)
  // after recurrence, cbuf region reused: obuf [0,2M)
  float* ws    = (float*)d_ws;
  float* cbuf  = ws;
  float* wallb = ws + (1 << 20);
  float* tmp   = ws + (2 << 20);
  float* mbuf  = tmp;
  unsigned long long* pz = (unsigned long long*)(ws + (3 << 20));
  float* obuf  = ws;

  float* outp   = (float*)d_out;
  float* watchp = outp + OUTS_ELEMS;
  float* susp   = watchp + WATCH_ELEMS;

  const dim3 blk(256);
  // logits = X @ attn_w + attn_b -> tmp   (MFMA split-bf16)
  gemm_mfma<<<dim3(8, 32), blk, 0, stream>>>(x, attn_w, attn_b, nullptr, tmp, 512, 512);
  // R = softmax(logits) * X   (in place on tmp)
  softmax_gate<<<dim3(2048), dim3(64), 0, stream>>>(tmp, x);
  // c = R @ in_w + in_b + ins_b -> cbuf
  gemm_mfma<<<dim3(8, 32), blk, 0, stream>>>(tmp, in_w, in_b, ins_b, cbuf, 512, 512);
  // sequential recurrence (no memset — epoch scheme replay-safe)
  recurrence<<<dim3(128), blk, 0, stream>>>(cbuf, ins_w, wallb, pz);
  // M = wall @ sus_w + sus_b -> mbuf ; out_small = wall @ out_w + out_b -> obuf
  gemm_dual_mfma<<<dim3(12, 32), blk, 0, stream>>>(wallb, sus_w, sus_b, mbuf,
                                                   out_w, out_b, obuf);
  // fused: sus scan (blocks 0-7, run under bc) + outs bc (268 MB) + watch bc
  finalize<<<dim3(4104), blk, 0, stream>>>(
      (const f32x4*)obuf, (f32x4*)d_out,
      (const f32x4*)(wallb + (127 << 13)), (const f32x4*)mbuf,
      (f32x4*)watchp, (f32x4*)susp);
}

// Round 18
// 328.008 us; speedup vs baseline: 1.1231x; 1.0574x over previous
//
#include <hip/hip_runtime.h>
#include <hip/hip_bf16.h>
#include <math.h>

// Problem: S=128, B=16, D=H=512, O=256.
// Collapse 1: watch/sus are exactly s-independent -> [16,512] recurrence;
//             outs broadcasts [128,16,256].
// Collapse 2: recurrence is row-independent -> 16 independent b-recurrences.
// Pipeline = R15 (MFMA prologue -> recurrence -> dual GEMM -> sus_scan ->
// finalize; separate epilogue kernels — R16/R17 fusion was net-negative).
// R18 change: recurrence uses 16 parts x 32 cols (256 WGs, 1/CU) to HALVE
// the per-CU per-step weight restream (64 KB vs 128 KB; 64 f32/thread may
// even go VGPR-resident). Sync structure identical to R15: thread tid polls
// pz[2tid,2tid+1] (exactly its wave's FMA k-range), wave-private wsm +
// lgkmcnt(0)+sched_barrier (rule #18), ONE syncthreads/step (parity-dbuf
// red). K-reduce: shfl_xor(32) + 4-wave LDS reduce; publishers tid<32.
// Epoch-in-data u64 (epoch<<32|f32 bits): 0xAA poison never matches epoch t;
// values deterministic -> stale/cross-replay matches are bit-identical/safe.
// GEMMs: MFMA split-bf16 (hi/lo, 3 mfma_16x16x32 per pair, ~2^-16 rel err).

#define S_LEN 128
#define B_SZ  16
#define H_SZ  512
#define O_SZ  256
#define ROWS  (S_LEN * B_SZ)   // 2048

#define OUTS_ELEMS  (S_LEN * S_LEN * B_SZ * O_SZ)   // 67,108,864
#define WATCH_ELEMS (S_LEN * B_SZ * H_SZ)           // 1,048,576

typedef float  f32x4  __attribute__((ext_vector_type(4)));
typedef __bf16 bf16x8 __attribute__((ext_vector_type(8)));

// ================= MFMA split-bf16 GEMM =====================================
struct alignas(16) GemmLds {
  __bf16 Ah[64][40]; __bf16 Al[64][40];
  __bf16 Bh[64][40]; __bf16 Bl[64][40];
};

__device__ __forceinline__ void gemm_body(
    const float* __restrict__ A, const float* __restrict__ B,
    const float* __restrict__ bias0, const float* __restrict__ bias1,
    float* __restrict__ C, int N, int K, int bm, int bn, GemmLds& T)
{
  const int tid = threadIdx.x;
  const int w = tid >> 6, l = tid & 63;
  const int fr = l & 15, fg = l >> 4;
  f32x4 acc[4] = {{0,0,0,0},{0,0,0,0},{0,0,0,0},{0,0,0,0}};
  const int ar = tid >> 2, ak = (tid & 3) << 3;   // A staging: row, k8
  const int bk = tid >> 3, bc = (tid & 7) << 3;   // B staging: k, col8

  for (int k0 = 0; k0 < K; k0 += 32) {
    {
      const float* s = &A[(size_t)(bm + ar) * K + k0 + ak];
      const f32x4 v0 = *(const f32x4*)s, v1 = *(const f32x4*)(s + 4);
      const float vv[8] = {v0.x, v0.y, v0.z, v0.w, v1.x, v1.y, v1.z, v1.w};
      bf16x8 h, lo;
#pragma unroll
      for (int j = 0; j < 8; ++j) {
        const __bf16 hh = (__bf16)vv[j];
        h[j] = hh; lo[j] = (__bf16)(vv[j] - (float)hh);
      }
      *(bf16x8*)&T.Ah[ar][ak] = h;
      *(bf16x8*)&T.Al[ar][ak] = lo;
    }
    {
      const float* s = &B[(size_t)(k0 + bk) * N + bn + bc];
      const f32x4 v0 = *(const f32x4*)s, v1 = *(const f32x4*)(s + 4);
      const float vv[8] = {v0.x, v0.y, v0.z, v0.w, v1.x, v1.y, v1.z, v1.w};
#pragma unroll
      for (int j = 0; j < 8; ++j) {
        const __bf16 hh = (__bf16)vv[j];
        T.Bh[bc + j][bk] = hh;
        T.Bl[bc + j][bk] = (__bf16)(vv[j] - (float)hh);
      }
    }
    __syncthreads();
    const bf16x8 ah = *(const bf16x8*)&T.Ah[(w << 4) + fr][fg << 3];
    const bf16x8 al = *(const bf16x8*)&T.Al[(w << 4) + fr][fg << 3];
#pragma unroll
    for (int nr = 0; nr < 4; ++nr) {
      const bf16x8 bh = *(const bf16x8*)&T.Bh[(nr << 4) + fr][fg << 3];
      const bf16x8 bl = *(const bf16x8*)&T.Bl[(nr << 4) + fr][fg << 3];
      acc[nr] = __builtin_amdgcn_mfma_f32_16x16x32_bf16(ah, bh, acc[nr], 0, 0, 0);
      acc[nr] = __builtin_amdgcn_mfma_f32_16x16x32_bf16(al, bh, acc[nr], 0, 0, 0);
      acc[nr] = __builtin_amdgcn_mfma_f32_16x16x32_bf16(ah, bl, acc[nr], 0, 0, 0);
    }
    __syncthreads();
  }
#pragma unroll
  for (int nr = 0; nr < 4; ++nr) {
    const int gcol = bn + (nr << 4) + fr;
    float bb = bias0 ? bias0[gcol] : 0.f;
    if (bias1) bb += bias1[gcol];
#pragma unroll
    for (int r = 0; r < 4; ++r) {
      const int grow = bm + (w << 4) + (fg << 2) + r;
      C[(size_t)grow * N + gcol] = acc[nr][r] + bb;
    }
  }
}

__global__ __launch_bounds__(256) void gemm_mfma(
    const float* __restrict__ A, const float* __restrict__ B,
    const float* __restrict__ bias0, const float* __restrict__ bias1,
    float* __restrict__ C, int N, int K)
{
  __shared__ GemmLds T;
  gemm_body(A, B, bias0, bias1, C, N, K, blockIdx.y << 6, blockIdx.x << 6, T);
}

__global__ __launch_bounds__(256) void gemm_dual_mfma(
    const float* __restrict__ A,
    const float* __restrict__ B1, const float* __restrict__ b1, float* __restrict__ C1,
    const float* __restrict__ B2, const float* __restrict__ b2, float* __restrict__ C2)
{
  __shared__ GemmLds T;
  if (blockIdx.x < 8)
    gemm_body(A, B1, b1, nullptr, C1, 512, 512, blockIdx.y << 6, blockIdx.x << 6, T);
  else
    gemm_body(A, B2, b2, nullptr, C2, 256, 512, blockIdx.y << 6, (blockIdx.x - 8) << 6, T);
}

// ---------------- softmax over H then gate by x (in-place on logits) --------
__global__ __launch_bounds__(64) void softmax_gate(float* __restrict__ lg,
                                                   const float* __restrict__ x)
{
  const int r = blockIdx.x;      // 0..2047
  const int lane = threadIdx.x;  // 0..63
  float v[8];
  float m = -1e30f;
#pragma unroll
  for (int i = 0; i < 8; ++i) {
    v[i] = lg[(r << 9) + (i << 6) + lane];
    m = fmaxf(m, v[i]);
  }
#pragma unroll
  for (int off = 32; off > 0; off >>= 1) m = fmaxf(m, __shfl_xor(m, off, 64));
  float s = 0.f;
#pragma unroll
  for (int i = 0; i < 8; ++i) { v[i] = expf(v[i] - m); s += v[i]; }
#pragma unroll
  for (int off = 32; off > 0; off >>= 1) s += __shfl_xor(s, off, 64);
  const float inv = 1.0f / s;
#pragma unroll
  for (int i = 0; i < 8; ++i) {
    const int idx = (r << 9) + (i << 6) + lane;
    lg[idx] = v[i] * inv * x[idx];
  }
}

// ---------------- recurrence: 256 WGs = 16 b x 16 parts (32 cols) -----------
// Wave kq owns K-range [128kq,128kq+128); lane l: col = 32p + (l&31),
// k-half h = l>>5 -> 64 weights/thread. Thread tid polls pz[2tid,2tid+1]
// (exactly its wave's k-range). K-reduce: shfl_xor(32) then 4-wave LDS
// reduce; publishers tid<32 (fan-in 1).
__global__ __launch_bounds__(256, 1) void recurrence(
    const float* __restrict__ cbuf,          // [128][16][512]
    const float* __restrict__ insw,          // [512][512]
    float* __restrict__ wall,                // [128][16][512]
    unsigned long long* __restrict__ pz)     // [16][16][512] u64 ring
{
  __shared__ float wsm[H_SZ];        // wave-private slices (wave kq: [128kq,+128))
  __shared__ float red[2][4][32];    // parity-dbuf cross-wave reduce

  const int wg  = blockIdx.x;
  const int b   = wg & 15;
  const int p   = wg >> 4;           // 0..15
  const int tid = threadIdx.x;
  const int l   = tid & 63;
  const int kq  = tid >> 6;          // wave 0..3
  const int colL = l & 31;
  const int h    = l >> 5;           // k-half within wave
  const int c   = (p << 5) + colL;   // owned col
  const int kb  = (kq << 7) + (h << 6);   // K base (64 k's)

  // weights: 64 f32/thread (may be VGPR-resident; else 64KB/step L2 restream)
  f32x4 wr[16];
#pragma unroll
  for (int j = 0; j < 16; ++j) {
    wr[j].x = insw[((kb + 4 * j + 0) << 9) + c];
    wr[j].y = insw[((kb + 4 * j + 1) << 9) + c];
    wr[j].z = insw[((kb + 4 * j + 2) << 9) + c];
    wr[j].w = insw[((kb + 4 * j + 3) << 9) + c];
  }

  // t = 0: publish w0 = tanh(c0) with epoch 1 in slot 0 (own 32 cols)
  if (tid < 32) {
    const float v = tanhf(cbuf[(b << 9) + c]);
    wall[(b << 9) + c] = v;
    const unsigned long long pk =
        (1ULL << 32) | (unsigned long long)__float_as_uint(v);
    __hip_atomic_store(&pz[(b << 9) + c], pk, __ATOMIC_RELAXED,
                       __HIP_MEMORY_SCOPE_AGENT);
  }

  for (int t = 1; t < S_LEN; ++t) {
    // prefetch c_t (only publishers use it)
    const float cv = cbuf[(t << 13) + (b << 9) + c];

    // wave-local poll: this wave's 64 lanes cover exactly [128kq,128kq+128)
    const unsigned long long* src =
        pz + (((t - 1) & 15) << 13) + (b << 9);
    unsigned long long v0, v1;
    for (;;) {
      v0 = __hip_atomic_load(&src[2 * tid], __ATOMIC_RELAXED,
                             __HIP_MEMORY_SCOPE_AGENT);
      v1 = __hip_atomic_load(&src[2 * tid + 1], __ATOMIC_RELAXED,
                             __HIP_MEMORY_SCOPE_AGENT);
      const bool ok = ((unsigned)(v0 >> 32) == (unsigned)t) &
                      ((unsigned)(v1 >> 32) == (unsigned)t);
      if (__ballot(ok) == ~0ULL) break;          // wave-local exit
    }
    // wave-private forwarding (only this wave reads this wsm range)
    wsm[2 * tid]     = __uint_as_float((unsigned)v0);
    wsm[2 * tid + 1] = __uint_as_float((unsigned)v1);
    asm volatile("s_waitcnt lgkmcnt(0)" ::: "memory");
    __builtin_amdgcn_sched_barrier(0);           // rule #18

    // partial dot over this lane's 64-k slice (reads: 2 b128 addrs/wave)
    float a0 = 0.f, a1 = 0.f, a2 = 0.f, a3 = 0.f;
#pragma unroll
    for (int j = 0; j < 16; ++j) {
      const f32x4 wv = *(const f32x4*)&wsm[kb + (j << 2)];
      a0 = fmaf(wr[j].x, wv.x, a0);
      a1 = fmaf(wr[j].y, wv.y, a1);
      a2 = fmaf(wr[j].z, wv.z, a2);
      a3 = fmaf(wr[j].w, wv.w, a3);
    }
    float z = (a0 + a1) + (a2 + a3);
    z += __shfl_xor(z, 32, 64);                  // add partner k-half
    if (l < 32) red[t & 1][kq][colL] = z;
    __syncthreads();                             // the ONE barrier per step
    if (tid < 32) {
      const float y = red[t & 1][0][tid] + red[t & 1][1][tid] +
                      red[t & 1][2][tid] + red[t & 1][3][tid];
      const float v = tanhf(cv + y);
      wall[(t << 13) + (b << 9) + c] = v;
      const unsigned long long pk =
          ((unsigned long long)(unsigned)(t + 1) << 32) |
          (unsigned long long)__float_as_uint(v);
      __hip_atomic_store(&pz[((t & 15) << 13) + (b << 9) + c], pk,
                         __ATOMIC_RELAXED, __HIP_MEMORY_SCOPE_AGENT);
    }
  }
}

// ---------------- sus scan (prefetch depth 4) -------------------------------
__global__ __launch_bounds__(256) void sus_scan(
    const float* __restrict__ M, float* __restrict__ s_small)
{
  const int gid = blockIdx.x * blockDim.x + threadIdx.x;  // 8192
  float s = 0.f;
  float n0 = M[gid];
  float n1 = M[(1 << 13) + gid];
  float n2 = M[(2 << 13) + gid];
  float n3 = M[(3 << 13) + gid];
  for (int t = 0; t < S_LEN - 4; ++t) {
    const float cur = n0;
    n0 = n1; n1 = n2; n2 = n3;
    n3 = M[((t + 4) << 13) + gid];
    s = tanhf(cur + s);
  }
  s = tanhf(n0 + s); s = tanhf(n1 + s); s = tanhf(n2 + s); s = tanhf(n3 + s);
  s_small[gid] = s;
}

// ---------------- finalize: outs + watch + sus broadcast --------------------
__global__ __launch_bounds__(256) void finalize(
    const f32x4* __restrict__ os4, f32x4* __restrict__ outs4,
    const f32x4* __restrict__ w127, const f32x4* __restrict__ s4,
    f32x4* __restrict__ watch_out, f32x4* __restrict__ sus_out)
{
  const int gid = blockIdx.x * blockDim.x + threadIdx.x;
  const int stride = gridDim.x * blockDim.x;
  for (int i = gid; i < (1 << 24); i += stride) {
    const int o4 = i & 63;
    const int b  = (i >> 6) & 15;
    const int t  = i >> 17;
    __builtin_nontemporal_store(os4[(((t << 4) + b) << 6) + o4], &outs4[i]);
  }
  if (gid < (1 << 18)) {
    const int src = gid & 2047;
    __builtin_nontemporal_store(w127[src], &watch_out[gid]);
    __builtin_nontemporal_store(s4[src], &sus_out[gid]);
  }
}

extern "C" void kernel_launch(void* const* d_in, const int* in_sizes, int n_in,
                              void* d_out, int out_size, void* d_ws, size_t ws_size,
                              hipStream_t stream)
{
  const float* x      = (const float*)d_in[0];
  const float* attn_w = (const float*)d_in[1];
  const float* attn_b = (const float*)d_in[2];
  const float* in_w   = (const float*)d_in[3];
  const float* in_b   = (const float*)d_in[4];
  const float* ins_w  = (const float*)d_in[5];
  const float* ins_b  = (const float*)d_in[6];
  const float* sus_w  = (const float*)d_in[7];
  const float* sus_b  = (const float*)d_in[8];
  const float* out_w  = (const float*)d_in[9];
  const float* out_b  = (const float*)d_in[10];

  // ws (bytes): cbuf [0,4M) | wall [4M,8M) | tmp->mbuf [8M,12M) | pz [12M,13M)
  // after recurrence, cbuf region reused: obuf [0,2M), s_small [2M,2M+32K)
  float* ws    = (float*)d_ws;
  float* cbuf  = ws;
  float* wallb = ws + (1 << 20);
  float* tmp   = ws + (2 << 20);
  float* mbuf  = tmp;
  unsigned long long* pz = (unsigned long long*)(ws + (3 << 20));
  float* obuf    = ws;
  float* s_small = ws + (1 << 19);

  float* outp   = (float*)d_out;
  float* watchp = outp + OUTS_ELEMS;
  float* susp   = watchp + WATCH_ELEMS;

  const dim3 blk(256);
  // logits = X @ attn_w + attn_b -> tmp   (MFMA split-bf16)
  gemm_mfma<<<dim3(8, 32), blk, 0, stream>>>(x, attn_w, attn_b, nullptr, tmp, 512, 512);
  // R = softmax(logits) * X   (in place on tmp)
  softmax_gate<<<dim3(2048), dim3(64), 0, stream>>>(tmp, x);
  // c = R @ in_w + in_b + ins_b -> cbuf
  gemm_mfma<<<dim3(8, 32), blk, 0, stream>>>(tmp, in_w, in_b, ins_b, cbuf, 512, 512);
  // sequential recurrence (no memset — epoch scheme replay-safe)
  recurrence<<<dim3(256), blk, 0, stream>>>(cbuf, ins_w, wallb, pz);
  // M = wall @ sus_w + sus_b -> mbuf ; out_small = wall @ out_w + out_b -> obuf
  gemm_dual_mfma<<<dim3(12, 32), blk, 0, stream>>>(wallb, sus_w, sus_b, mbuf,
                                                   out_w, out_b, obuf);
  // elementwise sus scan -> s_small
  sus_scan<<<dim3(32), blk, 0, stream>>>(mbuf, s_small);
  // outs broadcast (268 MB) + watch/sus broadcast (8 MB)
  finalize<<<dim3(4096), blk, 0, stream>>>(
      (const f32x4*)obuf, (f32x4*)d_out,
      (const f32x4*)(wallb + (127 << 13)), (const f32x4*)s_small,
      (f32x4*)watchp, (f32x4*)susp);
}